// Round 12
// baseline (640.676 us; speedup 1.0000x reference)
//
#include <hip/hip_runtime.h>
#include <math.h>

#define KS 5
#define K3 125

// problem sizes (fixed)
#define N0c 131072
#define N1c 65536
#define N2c 32768
#define N3c 16384
#define B8c 16384

typedef _Float16 hf8_t __attribute__((ext_vector_type(8)));
typedef _Float16 hf2_t __attribute__((ext_vector_type(2)));
typedef float f32x4_t __attribute__((ext_vector_type(4)));

union wpack_u { _Float16 h[8]; uint4 u; };
union u2h_u { unsigned u; hf2_t h; };

// ---------- helpers ----------
// quantized pseudo: q = rint(ps*65536) clamped to 65535; k0 = q>>14 (0..3), f = (q&16383)/16384.

__device__ __forceinline__ unsigned qz16(float ps) {
    float t = rintf(ps * 65536.0f);
    t = fminf(fmaxf(t, 0.0f), 65535.0f);
    return (unsigned)t;
}

// rows-space segment boundaries (row1,row2,row3,crow0,crow1,crow2,crow3)
#define SB1 65536
#define SB2 98304
#define SB3 114688
#define SB4 180224
#define SB5 212992
#define SB6 229376
#define SBT 245760

// coarse-bucket space: 512 keys per bucket
#define L2S 128
#define L3S 192
#define C0S 224
#define C1S 352
#define C2S 416
#define C3S 448
#define NBK 480

// ---------- W transpose + fp16: [bin][i][o] f32 -> [bin][o][i] fp16 ----------

__global__ void wtrans_kernel(const float* __restrict__ W2, const float* __restrict__ W3,
                              _Float16* __restrict__ WT2, _Float16* __restrict__ WT3) {
    int tid = blockIdx.x * blockDim.x + threadIdx.x;
    const int total = K3 * 1024;
    if (tid >= total) return;
    int bin = tid >> 10, r = tid & 1023, i = r >> 5, o = r & 31;
    WT2[bin * 1024 + o * 32 + i] = (_Float16)W2[tid];
    WT3[bin * 1024 + o * 32 + i] = (_Float16)W3[tid];
}

// ---------- coarse bucket id for item g ----------

__device__ __forceinline__ int coarse_bkt(long long g,
        const int* __restrict__ ei1, const int* __restrict__ ei2, const int* __restrict__ ei3,
        const int* __restrict__ cl0, const int* __restrict__ cl1,
        const int* __restrict__ cl2, const int* __restrict__ cl3,
        int E1, int E2, int E3) {
    long long Etot = (long long)E1 + E2 + E3;
    if (g < E1)                        return ei1[E1 + (int)g] >> 9;
    if (g < (long long)E1 + E2)        return L2S + (ei2[E2 + (int)(g - E1)] >> 9);
    if (g < Etot)                      return L3S + (ei3[E3 + (int)(g - E1 - E2)] >> 9);
    if (g < Etot + N0c)                return C0S + (cl0[(int)(g - Etot)] >> 9);
    if (g < Etot + N0c + N1c)          return C1S + (cl1[(int)(g - Etot - N0c)] >> 9);
    if (g < Etot + N0c + N1c + N2c)    return C2S + (cl2[(int)(g - Etot - N0c - N1c)] >> 9);
    return C3S + (cl3[(int)(g - Etot - N0c - N1c - N2c)] >> 9);
}

// ---------- phase A: coarse histogram ----------

__global__ __launch_bounds__(1024) void coarse_hist(
        const int* __restrict__ ei1, const int* __restrict__ ei2, const int* __restrict__ ei3,
        const int* __restrict__ cl0, const int* __restrict__ cl1,
        const int* __restrict__ cl2, const int* __restrict__ cl3,
        int* __restrict__ bcnt, int E1, int E2, int E3, int CH, long long IT) {
    __shared__ int l[NBK];
    int t = threadIdx.x;
    for (int i = t; i < NBK; i += 1024) l[i] = 0;
    __syncthreads();
    long long start = (long long)blockIdx.x * CH;
    long long end = start + CH; if (end > IT) end = IT;
    for (long long g = start + t; g < end; g += 1024)
        atomicAdd(&l[coarse_bkt(g, ei1, ei2, ei3, cl0, cl1, cl2, cl3, E1, E2, E3)], 1);
    __syncthreads();
    for (int i = t; i < NBK; i += 1024) if (l[i]) atomicAdd(&bcnt[i], l[i]);
}

// ---------- phase B: segmented scan of 480 bucket counts ----------

__global__ __launch_bounds__(512) void bucket_scan(const int* __restrict__ bcnt,
                                                   int* __restrict__ bbase,
                                                   int* __restrict__ rows,
                                                   int E1, int E2, int E3) {
    __shared__ int sdata[512];
    __shared__ int sseg[512];
    int t = threadIdx.x;
    int v = (t < NBK) ? bcnt[t] : 0;
    int seg = (t < L2S) ? 0 : (t < L3S) ? 1 : (t < C0S) ? 2 :
              (t < C1S) ? 3 : (t < C2S) ? 4 : (t < C3S) ? 5 : 6;
    sdata[t] = v; sseg[t] = seg;
    __syncthreads();
    for (int off = 1; off < 512; off <<= 1) {
        int add = (t >= off && sseg[t - off] == seg) ? sdata[t - off] : 0;
        __syncthreads();
        sdata[t] += add;
        __syncthreads();
    }
    if (t < NBK) bbase[t] = sdata[t] - v;
    if (t == 0) rows[SB1 + 0] = E1;
    if (t == 1) rows[SB2 + 1] = E2;
    if (t == 2) rows[SB3 + 2] = E3;
    if (t == 3) rows[SB4 + 3] = N0c;
    if (t == 4) rows[SB5 + 4] = N1c;
    if (t == 5) rows[SB6 + 5] = N2c;
    if (t == 6) rows[SBT + 6] = N3c;
}

// ---------- phase C: two-sweep coarse scatter ----------
// edge rec (uint4): {q0|q1<<16, q2|dst<<16, src, 0}; cluster rec (uint2): {node, bin}.

__global__ __launch_bounds__(1024) void scatter_coarse(
        const int* __restrict__ ei1, const int* __restrict__ ei2, const int* __restrict__ ei3,
        const float* __restrict__ ps1, const float* __restrict__ ps2, const float* __restrict__ ps3,
        const int* __restrict__ cl0, const int* __restrict__ cl1,
        const int* __restrict__ cl2, const int* __restrict__ cl3,
        const int* __restrict__ bbase, int* __restrict__ gcur, int* __restrict__ ccnt,
        uint4* __restrict__ qe, uint2* __restrict__ qc,
        int E1, int E2, int E3, int CH, long long IT) {
    __shared__ int lcnt[NBK];
    __shared__ int gb[NBK];
    __shared__ int lcell[128];
    int t = threadIdx.x;
    for (int i = t; i < NBK; i += 1024) lcnt[i] = 0;
    if (t < 128) lcell[t] = 0;
    __syncthreads();
    long long start = (long long)blockIdx.x * CH;
    long long end = start + CH; if (end > IT) end = IT;
    long long Etot = (long long)E1 + E2 + E3;

    for (long long g = start + t; g < end; g += 1024)
        atomicAdd(&lcnt[coarse_bkt(g, ei1, ei2, ei3, cl0, cl1, cl2, cl3, E1, E2, E3)], 1);
    __syncthreads();
    for (int i = t; i < NBK; i += 1024) {
        gb[i] = lcnt[i] ? atomicAdd(&gcur[i], lcnt[i]) : 0;
        lcnt[i] = 0;
    }
    __syncthreads();

    for (long long g = start + t; g < end; g += 1024) {
        if (g < Etot) {
            int e, dst, src, bkt, qoff;
            const float* ps;
            if (g < E1)      { e = (int)g;           dst = ei1[E1 + e]; src = ei1[e]; ps = ps1; bkt = dst >> 9;         qoff = 0; }
            else if (g < (long long)E1 + E2)
                             { e = (int)(g - E1);    dst = ei2[E2 + e]; src = ei2[e]; ps = ps2; bkt = L2S + (dst >> 9); qoff = E1; }
            else             { e = (int)(g - E1 - E2); dst = ei3[E3 + e]; src = ei3[e]; ps = ps3; bkt = L3S + (dst >> 9); qoff = E1 + E2; }
            unsigned q0 = qz16(ps[(size_t)e * 3]);
            unsigned q1 = qz16(ps[(size_t)e * 3 + 1]);
            unsigned q2 = qz16(ps[(size_t)e * 3 + 2]);
            int r = atomicAdd(&lcnt[bkt], 1);
            qe[qoff + bbase[bkt] + gb[bkt] + r] =
                make_uint4(q0 | (q1 << 16), q2 | ((unsigned)dst << 16), (unsigned)src, 0u);
            if (g >= E1) {
                int cell = (int)(((q0 >> 14) << 4) | ((q1 >> 14) << 2) | (q2 >> 14));
                atomicAdd(&lcell[(g < (long long)E1 + E2) ? cell : 64 + cell], 1);
            }
        } else {
            int i, bin, bkt, qoff;
            if (g < Etot + N0c)             { i = (int)(g - Etot);                   bin = cl0[i]; bkt = C0S + (bin >> 9); qoff = 0; }
            else if (g < Etot + N0c + N1c)  { i = (int)(g - Etot - N0c);             bin = cl1[i]; bkt = C1S + (bin >> 9); qoff = N0c; }
            else if (g < Etot + N0c + N1c + N2c)
                                            { i = (int)(g - Etot - N0c - N1c);       bin = cl2[i]; bkt = C2S + (bin >> 9); qoff = N0c + N1c; }
            else                            { i = (int)(g - Etot - N0c - N1c - N2c); bin = cl3[i]; bkt = C3S + (bin >> 9); qoff = N0c + N1c + N2c; }
            int r = atomicAdd(&lcnt[bkt], 1);
            qc[qoff + bbase[bkt] + gb[bkt] + r] = make_uint2((unsigned)i, (unsigned)bin);
        }
    }
    __syncthreads();
    if (t < 128 && lcell[t]) atomicAdd(&ccnt[t], lcell[t]);
}

// ---------- coff + blockcell from cell counts ----------

__global__ void coff_build(const int* __restrict__ ccnt, int* __restrict__ coff,
                           int* __restrict__ blockcell2, int* __restrict__ blockcell3) {
    int t = threadIdx.x;
    if (t == 0) {
        int acc = 0;
        for (int c = 0; c < 64; c++) {
            coff[c] = acc;
            int nbk = (ccnt[c] + 255) >> 8;
            for (int k = 0; k < nbk; k++) blockcell2[(acc >> 8) + k] = c;
            acc += nbk << 8;
        }
    }
    if (t == 1) {
        int acc = 0;
        for (int c = 0; c < 64; c++) {
            coff[64 + c] = acc;
            int nbk = (ccnt[64 + c] + 255) >> 8;
            for (int k = 0; k < nbk; k++) blockcell3[(acc >> 8) + k] = c;
            acc += nbk << 8;
        }
    }
}

// ---------- phase D: per-bucket fine pass ----------
// lvl1: precompute fp16 corner-weight pairs {w0,w4},{w2,w6},{w1,w5},{w3,w7} (wpay1)
//       + meta1 = f0<<16 | src. lvl2/3: vpay+dpos. clusters: mem lists.

__global__ __launch_bounds__(1024) void pass2_all(
        const uint4* __restrict__ qe, const uint2* __restrict__ qc,
        const int* __restrict__ bbase, const int* __restrict__ bcnt,
        int* __restrict__ rows,
        uint4* __restrict__ wpay1, int* __restrict__ meta1,
        uint2* __restrict__ vpay2, int* __restrict__ dpos2,
        uint2* __restrict__ vpay3, int* __restrict__ dpos3,
        int* __restrict__ mem0, int* __restrict__ mem1,
        int* __restrict__ mem2, int* __restrict__ mem3,
        int* __restrict__ ccur, const int* __restrict__ coff,
        int E1, int E2, int E3) {
    __shared__ int scnt[512];
    __shared__ int rowv[512];
    __shared__ int scur[512];
    __shared__ int lcell[64];
    __shared__ int gcb[64];
    __shared__ int ccur_l[64];
    int t = threadIdx.x;
    int b = blockIdx.x;

    int kind, lb;
    const uint4* qr = nullptr; const uint2* cr = nullptr;
    int* rowp; uint2* vp = nullptr; int* dp = nullptr; int* memp = nullptr;
    int cofs = 0;
    if (b < L2S)      { kind = 1; lb = b;       qr = qe + bbase[b];             rowp = rows; }
    else if (b < L3S) { kind = 2; lb = b - L2S; qr = qe + E1 + bbase[b];        rowp = rows + SB1 + 1; vp = vpay2; dp = dpos2; cofs = 0; }
    else if (b < C0S) { kind = 3; lb = b - L3S; qr = qe + E1 + E2 + bbase[b];   rowp = rows + SB2 + 2; vp = vpay3; dp = dpos3; cofs = 64; }
    else if (b < C1S) { kind = 4; lb = b - C0S; cr = qc + bbase[b];             rowp = rows + SB3 + 3; memp = mem0; }
    else if (b < C2S) { kind = 5; lb = b - C1S; cr = qc + N0c + bbase[b];       rowp = rows + SB4 + 4; memp = mem1; }
    else if (b < C3S) { kind = 6; lb = b - C2S; cr = qc + N0c + N1c + bbase[b]; rowp = rows + SB5 + 5; memp = mem2; }
    else              { kind = 7; lb = b - C3S; cr = qc + N0c + N1c + N2c + bbase[b]; rowp = rows + SB6 + 6; memp = mem3; }
    int n = bcnt[b];
    int ebase = bbase[b];
    int rowoff = lb << 9;

    if (t < 512) { scnt[t] = 0; scur[t] = 0; }
    if (t < 64) { lcell[t] = 0; ccur_l[t] = 0; }
    __syncthreads();

    // sweep 1: count fine bins (+cells for edge lvl2/3)
    if (kind <= 3) {
        for (int i = t; i < n; i += 1024) {
            uint4 r = qr[i];
            atomicAdd(&scnt[(r.y >> 16) & 511], 1);
            if (kind >= 2) {
                int cell = (int)((((r.x & 0xFFFFu) >> 14) << 4) | ((r.x >> 30) << 2) | ((r.y & 0xFFFFu) >> 14));
                atomicAdd(&lcell[cell], 1);
            }
        }
    } else {
        for (int i = t; i < n; i += 1024) {
            uint2 r = cr[i];
            atomicAdd(&scnt[r.y & 511], 1);
        }
    }
    __syncthreads();

    // exclusive scan of 512 bins; write row offsets
    {
        int v = (t < 512) ? scnt[t] : 0;
        if (t < 512) rowv[t] = v;
        __syncthreads();
        for (int off = 1; off < 512; off <<= 1) {
            int add = (t >= off && t < 512) ? rowv[t - off] : 0;
            __syncthreads();
            if (t < 512) rowv[t] += add;
            __syncthreads();
        }
        if (t < 512) {
            int base = ebase + rowv[t] - v;
            rowv[t] = base;
            rowp[rowoff + t] = base;
        }
    }
    if (kind >= 2 && kind <= 3 && t < 64)
        gcb[t] = lcell[t] ? atomicAdd(&ccur[cofs + t], lcell[t]) : 0;
    __syncthreads();

    // sweep 2: place
    if (kind == 1) {
        const float inv = 1.0f / 16384.0f;
        for (int i = t; i < n; i += 1024) {
            uint4 r = qr[i];
            int d9 = (r.y >> 16) & 511;
            int pos = rowv[d9] + atomicAdd(&scur[d9], 1);
            int k0 = (int)((r.x & 0xFFFFu) >> 14);
            int k1 = (int)(r.x >> 30);
            int k2 = (int)((r.y & 0xFFFFu) >> 14);
            float fx = (float)(r.x & 16383u) * inv;
            float fy = (float)((r.x >> 16) & 16383u) * inv;
            float fz = (float)(r.y & 16383u) * inv;
            float gx = 1.0f - fx, gy = 1.0f - fy, gz = 1.0f - fz;
            int f0 = (k0 * 5 + k1) * 5 + k2;
            wpack_u pk;
            // pairs along z: {w0,w4},{w2,w6},{w1,w5},{w3,w7}
            pk.h[0] = (_Float16)(gx * gy * gz); pk.h[1] = (_Float16)(gx * gy * fz);
            pk.h[2] = (_Float16)(gx * fy * gz); pk.h[3] = (_Float16)(gx * fy * fz);
            pk.h[4] = (_Float16)(fx * gy * gz); pk.h[5] = (_Float16)(fx * gy * fz);
            pk.h[6] = (_Float16)(fx * fy * gz); pk.h[7] = (_Float16)(fx * fy * fz);
            wpay1[pos] = pk.u;
            meta1[pos] = (int)(r.z | ((unsigned)f0 << 16));
        }
    } else if (kind <= 3) {
        for (int i = t; i < n; i += 1024) {
            uint4 r = qr[i];
            int d9 = (r.y >> 16) & 511;
            int dpv = rowv[d9] + atomicAdd(&scur[d9], 1);
            int cell = (int)((((r.x & 0xFFFFu) >> 14) << 4) | ((r.x >> 30) << 2) | ((r.y & 0xFFFFu) >> 14));
            int cl = atomicAdd(&ccur_l[cell], 1);
            int slot = coff[cofs + cell] + gcb[cell] + cl;
            vp[slot] = make_uint2(r.x, (r.y & 0xFFFFu) | (r.z << 16));
            dp[slot] = dpv;
        }
    } else {
        for (int i = t; i < n; i += 1024) {
            uint2 r = cr[i];
            int b9 = r.y & 511;
            memp[rowv[b9] + atomicAdd(&scur[b9], 1)] = (int)r.x;
        }
    }
}

// ---------- pooling ----------

__global__ void pool1ch_kernel(const float* __restrict__ in, const int* __restrict__ crow,
                               const int* __restrict__ mem, float* __restrict__ out, int n) {
    int nd = blockIdx.x * blockDim.x + threadIdx.x;
    if (nd >= n) return;
    int beg = crow[nd], end = crow[nd + 1];
    float v = -INFINITY;
    for (int p = beg; p < end; p++) v = fmaxf(v, in[mem[p]]);
    out[nd] = (beg == end) ? 0.0f : v;
}

__global__ void pool32ch_kernel(const float* __restrict__ in, const int* __restrict__ crow,
                                const int* __restrict__ mem, float* __restrict__ out, int n) {
    int tid = blockIdx.x * blockDim.x + threadIdx.x;
    int nd = tid >> 5, o = tid & 31;
    if (nd >= n) return;
    int beg = crow[nd], end = crow[nd + 1];
    float v = -INFINITY;
    for (int p = beg; p < end; p++) v = fmaxf(v, in[(size_t)mem[p] * 32 + o]);
    out[(size_t)nd * 32 + o] = (beg == end) ? 0.0f : v;
}

// ---------- cell conv via MFMA fp16, quantized payload ----------

__global__ __launch_bounds__(256, 4) void conv_cell_mfma(
        const float* __restrict__ x, const uint2* __restrict__ vpay, const int* __restrict__ dposA,
        const int* __restrict__ blockcell, const _Float16* __restrict__ WT,
        _Float16* __restrict__ y, int E) {
    __shared__ _Float16 Wl[8 * 1024];   // [c][o][i]  16 KB
    __shared__ _Float16 xh[256 * 32];   // [e][i]     16 KB
    __shared__ uint4 wcl[256];          // w8 per edge  4 KB
    __shared__ int dinfo[256];

    int cell = blockcell[blockIdx.x];
    if (cell < 0) return;

    int t = threadIdx.x;
    int base = blockIdx.x * 256;
    uint2 vq = vpay[base + t];
    int d = dposA[base + t];
    dinfo[t] = d;
    int src = (d < 0) ? 0 : (int)(vq.y >> 16);

    {
        const float inv = 1.0f / 16384.0f;
        float fx = (float)(vq.x & 16383u) * inv;
        float fy = (float)((vq.x >> 16) & 16383u) * inv;
        float fz = (float)(vq.y & 16383u) * inv;
        float gx0 = 1.0f - fx, gy0 = 1.0f - fy, gz0 = 1.0f - fz;
        wpack_u pk;
        pk.h[0] = (_Float16)(gx0 * gy0 * gz0);
        pk.h[1] = (_Float16)(fx  * gy0 * gz0);
        pk.h[2] = (_Float16)(gx0 * fy  * gz0);
        pk.h[3] = (_Float16)(fx  * fy  * gz0);
        pk.h[4] = (_Float16)(gx0 * gy0 * fz );
        pk.h[5] = (_Float16)(fx  * gy0 * fz );
        pk.h[6] = (_Float16)(gx0 * fy  * fz );
        pk.h[7] = (_Float16)(fx  * fy  * fz );
        wcl[t] = pk.u;
    }

    {
        int kx = cell >> 4, ky = (cell >> 2) & 3, kz = cell & 3;
        int c = t >> 5, o = t & 31;
        int id0 = kx + ((c >> 0) & 1);
        int id1 = ky + ((c >> 1) & 1);
        int id2 = kz + ((c >> 2) & 1);
        int flat = (id0 * KS + id1) * KS + id2;
        const uint4* s4 = (const uint4*)(WT + (size_t)flat * 1024 + o * 32);
        uint4* dst = (uint4*)&Wl[c * 1024 + o * 32];
        #pragma unroll
        for (int j = 0; j < 4; j++) dst[j] = s4[j];
    }

    {
        const float4* xr = (const float4*)(x + (size_t)src * 32);
        _Float16* xd = &xh[t * 32];
        #pragma unroll
        for (int j = 0; j < 8; j++) {
            float4 v = xr[j];
            xd[j * 4 + 0] = (_Float16)v.x;
            xd[j * 4 + 1] = (_Float16)v.y;
            xd[j * 4 + 2] = (_Float16)v.z;
            xd[j * 4 + 3] = (_Float16)v.w;
        }
    }
    __syncthreads();

    int wv = t >> 6, lane = t & 63;
    int quad = lane >> 4, mrow = lane & 15;
    const _Float16* whal = (const _Float16*)wcl;

    hf8_t xf[4];
    #pragma unroll
    for (int mt = 0; mt < 4; mt++) {
        int em = wv * 64 + mt * 16 + mrow;
        xf[mt] = *(const hf8_t*)&xh[em * 32 + quad * 8];
    }

    f32x4_t acc[4][2];
    #pragma unroll
    for (int mt = 0; mt < 4; mt++) {
        acc[mt][0] = (f32x4_t)0.0f;
        acc[mt][1] = (f32x4_t)0.0f;
    }

    #pragma unroll
    for (int c = 0; c < 8; c++) {
        hf8_t b0 = *(const hf8_t*)&Wl[c * 1024 + mrow * 32 + quad * 8];
        hf8_t b1 = *(const hf8_t*)&Wl[c * 1024 + (16 + mrow) * 32 + quad * 8];
        #pragma unroll
        for (int mt = 0; mt < 4; mt++) {
            int em = wv * 64 + mt * 16 + mrow;
            _Float16 wcv = whal[em * 8 + c];
            hf8_t af = xf[mt] * wcv;
            acc[mt][0] = __builtin_amdgcn_mfma_f32_16x16x32_f16(af, b0, acc[mt][0], 0, 0, 0);
            acc[mt][1] = __builtin_amdgcn_mfma_f32_16x16x32_f16(af, b1, acc[mt][1], 0, 0, 0);
        }
    }

    #pragma unroll
    for (int mt = 0; mt < 4; mt++) {
        #pragma unroll
        for (int reg = 0; reg < 4; reg++) {
            int el = wv * 64 + mt * 16 + quad * 4 + reg;
            int dd = dinfo[el];
            if (dd >= 0) {
                y[(size_t)dd * 32 + mrow]      = (_Float16)acc[mt][0][reg];
                y[(size_t)dd * 32 + 16 + mrow] = (_Float16)acc[mt][1][reg];
            }
        }
    }
}

// ---------- gather finalize ----------

__global__ void gather_fin_kernel(const _Float16* __restrict__ y, const int* __restrict__ row_start,
                                  const float* __restrict__ x, const float* __restrict__ root,
                                  const float* __restrict__ b, float* __restrict__ out, int n) {
    int tid = blockIdx.x * blockDim.x + threadIdx.x;
    int nd = tid >> 5, o = tid & 31;
    if (nd >= n) return;
    int beg = row_start[nd], end = row_start[nd + 1];
    float acc = 0.0f;
    for (int p = beg; p < end; p++) acc += (float)y[(size_t)p * 32 + o];
    acc /= fmaxf((float)(end - beg), 1.0f);
    const float* __restrict__ xr = x + (size_t)nd * 32;
    float rsum = 0.0f;
    #pragma unroll
    for (int i = 0; i < 32; i++) rsum += xr[i] * root[i * 32 + o];
    float v = acc + rsum + b[o];
    out[(size_t)nd * 32 + o] = (v > 0.0f) ? v : expm1f(v);
}

// ---------- conv1: precomputed fp16 weight pairs, half2 W pairs in LDS ----------

__global__ __launch_bounds__(256) void conv1_node_kernel(
        const float* __restrict__ x, const uint4* __restrict__ wpay1,
        const int* __restrict__ meta1, const int* __restrict__ row_start,
        const float* __restrict__ W, const float* __restrict__ root,
        const float* __restrict__ b, float* __restrict__ out, int n) {
    // Wp[o*125+bin] = half2(W[bin][o], W[bin+1][o]); stride 125 words -> conflict-free
    __shared__ unsigned Wp[32 * K3];   // 16 KB
    for (int i = threadIdx.x; i < 32 * K3; i += 256) {
        int o = i / K3, bin = i - o * K3;
        u2h_u v;
        v.h[0] = (_Float16)W[bin * 32 + o];
        v.h[1] = (bin < K3 - 1) ? (_Float16)W[(bin + 1) * 32 + o] : (_Float16)0.0f;
        Wp[i] = v.u;
    }
    __syncthreads();

    int tid = blockIdx.x * blockDim.x + threadIdx.x;
    int nd = tid >> 5, o = tid & 31;
    if (nd >= n) return;
    int beg = row_start[nd], end = row_start[nd + 1];
    const unsigned* Wo = &Wp[o * K3];
    float acc = 0.0f;
    for (int idx = beg; idx < end; idx++) {
        uint4 wv = wpay1[idx];
        int meta = meta1[idx];
        int src = meta & 0xFFFF;
        int f0 = meta >> 16;
        u2h_u p0, p1, p2, p3, w0, w1, w2, w3;
        p0.u = wv.x; p1.u = wv.y; p2.u = wv.z; p3.u = wv.w;
        w0.u = Wo[f0]; w1.u = Wo[f0 + 5]; w2.u = Wo[f0 + 25]; w3.u = Wo[f0 + 30];
        hf2_t s2 = p0.h * w0.h;
        s2 += p1.h * w1.h;
        s2 += p2.h * w2.h;
        s2 += p3.h * w3.h;
        float s = (float)s2[0] + (float)s2[1];
        acc += x[src] * s;
    }
    float v = acc / fmaxf((float)(end - beg), 1.0f) + x[nd] * root[o] + b[o];
    out[(size_t)nd * 32 + o] = (v > 0.0f) ? v : expm1f(v);
}

// ---------- FC + log_softmax ----------

__global__ void fc_kernel(const float* __restrict__ h, const float* __restrict__ fw,
                          const float* __restrict__ fb, float* __restrict__ out, int B) {
    int tid = blockIdx.x * blockDim.x + threadIdx.x;
    int row = tid >> 5, lane = tid & 31;
    if (row >= B) return;
    const float* hb = h + (size_t)row * 256;
    float lg[10];
    #pragma unroll
    for (int j = 0; j < 10; j++) lg[j] = 0.0f;
    for (int tt = lane; tt < 256; tt += 32) {
        float hv = hb[tt];
        const float* fr = fw + tt * 10;
        #pragma unroll
        for (int j = 0; j < 10; j++) lg[j] += hv * fr[j];
    }
    #pragma unroll
    for (int off = 16; off > 0; off >>= 1)
        #pragma unroll
        for (int j = 0; j < 10; j++) lg[j] += __shfl_down(lg[j], off, 32);
    if (lane == 0) {
        #pragma unroll
        for (int j = 0; j < 10; j++) lg[j] += fb[j];
        float m = lg[0];
        #pragma unroll
        for (int j = 1; j < 10; j++) m = fmaxf(m, lg[j]);
        float s = 0.0f;
        #pragma unroll
        for (int j = 0; j < 10; j++) s += expf(lg[j] - m);
        float lse = logf(s) + m;
        #pragma unroll
        for (int j = 0; j < 10; j++) out[(size_t)row * 10 + j] = lg[j] - lse;
    }
}

// ---------- launch ----------

static inline int cdiv(long long a, int b) { return (int)((a + b - 1) / b); }

extern "C" void kernel_launch(void* const* d_in, const int* in_sizes, int n_in,
                              void* d_out, int out_size, void* d_ws, size_t ws_size,
                              hipStream_t stream) {
    const int N1 = N1c, N2 = N2c, N3 = N3c, B8 = B8c;
    const int B = B8 / 8;

    const float* x      = (const float*)d_in[0];
    const int*   cl0    = (const int*)d_in[1];
    const int*   ei1    = (const int*)d_in[2];
    const float* ps1    = (const float*)d_in[3];
    const int*   cl1    = (const int*)d_in[4];
    const int*   ei2    = (const int*)d_in[5];
    const float* ps2    = (const float*)d_in[6];
    const int*   cl2    = (const int*)d_in[7];
    const int*   ei3    = (const int*)d_in[8];
    const float* ps3    = (const float*)d_in[9];
    const int*   cl3    = (const int*)d_in[10];
    const float* W1     = (const float*)d_in[11];
    const float* root1  = (const float*)d_in[12];
    const float* b1     = (const float*)d_in[13];
    const float* W2     = (const float*)d_in[14];
    const float* root2  = (const float*)d_in[15];
    const float* b2     = (const float*)d_in[16];
    const float* W3     = (const float*)d_in[17];
    const float* root3  = (const float*)d_in[18];
    const float* b3     = (const float*)d_in[19];
    const float* fc_w   = (const float*)d_in[20];
    const float* fc_b   = (const float*)d_in[21];
    float* out = (float*)d_out;

    const int E1 = in_sizes[2] / 2;
    const int E2 = in_sizes[5] / 2;
    const int E3 = in_sizes[8] / 2;
    const long long Etot = (long long)E1 + E2 + E3;
    const long long IT = Etot + N0c + N1c + N2c + N3c;

    const int grid2 = cdiv((long long)E2 + 64 * 255, 256);
    const int grid3 = cdiv((long long)E3 + 64 * 255, 256);
    const int pad2 = grid2 * 256, pad3 = grid3 * 256;
    const int ymax = (E2 > E3 ? E2 : E3);

    // ---- workspace layout ----
    char* wp = (char*)d_ws;
    float* p0  = (float*)wp;               wp += (size_t)N1 * 4;
    float* h1  = (float*)wp;               wp += (size_t)N1 * 32 * 4;
    float* p1  = (float*)wp;               wp += (size_t)N2 * 32 * 4;
    float* h2  = (float*)wp;               wp += (size_t)N2 * 32 * 4;
    float* p2  = (float*)wp;               wp += (size_t)N3 * 32 * 4;
    float* h3  = (float*)wp;               wp += (size_t)N3 * 32 * 4;
    float* p3  = (float*)wp;               wp += (size_t)B8 * 32 * 4;
    // zeroed-together region: [bcnt | gcur | ccnt | ccur]
    int* bcnt  = (int*)wp;                 wp += NBK * 4;
    int* gcur  = (int*)wp;                 wp += NBK * 4;
    int* ccnt  = (int*)wp;                 wp += 128 * 4;
    int* ccur  = (int*)wp;                 wp += 128 * 4;
    size_t zero_bytes = (size_t)(wp - (char*)bcnt);
    int* bbase = (int*)wp;                 wp += NBK * 4;
    int* coff  = (int*)wp;                 wp += 128 * 4;
    int* rows  = (int*)wp;                 wp += (size_t)(SBT + 7) * 4;
    int* mem0  = (int*)wp;                 wp += (size_t)N0c * 4;
    int* mem1  = (int*)wp;                 wp += (size_t)N1c * 4;
    int* mem2  = (int*)wp;                 wp += (size_t)N2c * 4;
    int* mem3  = (int*)wp;                 wp += (size_t)N3c * 4;
    uint4* wpay1 = (uint4*)wp;             wp += (size_t)E1 * 16;
    int* meta1   = (int*)wp;               wp += (size_t)E1 * 4;
    uint4* qe    = (uint4*)wp;             wp += (size_t)Etot * 16;
    uint2* qc    = (uint2*)wp;             wp += (size_t)(N0c + N1c + N2c + N3c) * 8;
    uint2* vpay2 = (uint2*)wp;             wp += (size_t)pad2 * 8;
    uint2* vpay3 = (uint2*)wp;             wp += (size_t)pad3 * 8;
    int* dpos2 = (int*)wp;                 wp += (size_t)pad2 * 4;
    int* dpos3 = (int*)wp;                 wp += (size_t)pad3 * 4;   // contiguous with dpos2
    int* blockcell2 = (int*)wp;            wp += (size_t)grid2 * 4;
    int* blockcell3 = (int*)wp;            wp += (size_t)grid3 * 4;  // contiguous with blockcell2
    _Float16* WT2 = (_Float16*)wp;         wp += (size_t)K3 * 1024 * 2;
    _Float16* WT3 = (_Float16*)wp;         wp += (size_t)K3 * 1024 * 2;
    _Float16* yh = (_Float16*)wp;          // ymax*32 halves

    int* row1  = rows;
    int* row2  = rows + SB1 + 1;
    int* row3  = rows + SB2 + 2;
    int* crow0 = rows + SB3 + 3;
    int* crow1 = rows + SB4 + 4;
    int* crow2 = rows + SB5 + 5;
    int* crow3 = rows + SB6 + 6;

    const int T = 256;
    const int CH = 16384;
    const int gridC = cdiv(IT, CH);

    // ========== indexing phase ==========
    hipMemsetAsync(bcnt, 0, zero_bytes, stream);
    hipMemsetAsync(dpos2, 0xFF, ((size_t)pad2 + pad3) * 4, stream);
    hipMemsetAsync(blockcell2, 0xFF, ((size_t)grid2 + grid3) * 4, stream);
    wtrans_kernel<<<cdiv((long long)K3 * 1024, T), T, 0, stream>>>(W2, W3, WT2, WT3);
    coarse_hist<<<gridC, 1024, 0, stream>>>(ei1, ei2, ei3, cl0, cl1, cl2, cl3,
                                            bcnt, E1, E2, E3, CH, IT);
    bucket_scan<<<1, 512, 0, stream>>>(bcnt, bbase, rows, E1, E2, E3);
    scatter_coarse<<<gridC, 1024, 0, stream>>>(
        ei1, ei2, ei3, ps1, ps2, ps3, cl0, cl1, cl2, cl3,
        bbase, gcur, ccnt, qe, qc, E1, E2, E3, CH, IT);
    coff_build<<<1, 64, 0, stream>>>(ccnt, coff, blockcell2, blockcell3);
    pass2_all<<<NBK, 1024, 0, stream>>>(
        qe, qc, bbase, bcnt, rows, wpay1, meta1, vpay2, dpos2, vpay3, dpos3,
        mem0, mem1, mem2, mem3, ccur, coff, E1, E2, E3);

    // ========== pipeline ==========
    pool1ch_kernel<<<cdiv(N1, T), T, 0, stream>>>(x, crow0, mem0, p0, N1);

    conv1_node_kernel<<<cdiv((long long)N1 * 32, T), T, 0, stream>>>(
        p0, wpay1, meta1, row1, W1, root1, b1, h1, N1);

    pool32ch_kernel<<<cdiv((long long)N2 * 32, T), T, 0, stream>>>(h1, crow1, mem1, p1, N2);

    conv_cell_mfma<<<grid2, 256, 0, stream>>>(p1, vpay2, dpos2, blockcell2, WT2, yh, E2);
    gather_fin_kernel<<<cdiv((long long)N2 * 32, T), T, 0, stream>>>(
        yh, row2, p1, root2, b2, h2, N2);

    pool32ch_kernel<<<cdiv((long long)N3 * 32, T), T, 0, stream>>>(h2, crow2, mem2, p2, N3);

    conv_cell_mfma<<<grid3, 256, 0, stream>>>(p2, vpay3, dpos3, blockcell3, WT3, yh, E3);
    gather_fin_kernel<<<cdiv((long long)N3 * 32, T), T, 0, stream>>>(
        yh, row3, p2, root3, b3, h3, N3);

    pool32ch_kernel<<<cdiv((long long)B8 * 32, T), T, 0, stream>>>(h3, crow3, mem3, p3, B8);

    fc_kernel<<<cdiv((long long)B * 32, T), T, 0, stream>>>(p3, fc_w, fc_b, out, B);
}